// Round 1
// 322.668 us; speedup vs baseline: 1.0011x; 1.0011x over previous
//
#include <hip/hip_runtime.h>
#include <algorithm>

// JAX >= 0.5 partitionable threefry (verified absmax=0 previously).
// sel = jax.random.permutation(key(42), degrees)[:ns] is input-independent,
// so it's computed on the HOST in kernel_launch (same work every call; values
// baked into kernel args at graph capture — constant across replays, correct).

static inline void tf2x32_host(unsigned k0, unsigned k1, unsigned c0, unsigned c1,
                               unsigned& o0, unsigned& o1) {
  const unsigned ks0 = k0, ks1 = k1, ks2 = k0 ^ k1 ^ 0x1BD11BDAu;
  unsigned x0 = c0 + ks0, x1 = c1 + ks1;
#define TF_R(r) { x0 += x1; x1 = (x1 << (r)) | (x1 >> (32 - (r))); x1 ^= x0; }
  TF_R(13) TF_R(15) TF_R(26) TF_R(6)   x0 += ks1; x1 += ks2 + 1u;
  TF_R(17) TF_R(29) TF_R(16) TF_R(24)  x0 += ks2; x1 += ks0 + 2u;
  TF_R(13) TF_R(15) TF_R(26) TF_R(6)   x0 += ks0; x1 += ks1 + 3u;
  TF_R(17) TF_R(29) TF_R(16) TF_R(24)  x0 += ks1; x1 += ks2 + 4u;
  TF_R(13) TF_R(15) TF_R(26) TF_R(6)   x0 += ks2; x1 += ks0 + 5u;
#undef TF_R
  o0 = x0; o1 = x1;
}

#define MAX_NS 64

struct SelArgs { int v[MAX_NS]; };

// Direct per-output gather: one thread per output element.
//   out[r*ns + j] = adj[base + ids[r]*degrees + sel[j]]
// Rationale vs the previous LDS-staged version:
//   - 32 random cols of 128 touch ~7.9 of the 8 64B lines of each 512B row,
//     so the scattered 4B loads fetch the SAME HBM lines as a full-row read.
//   - Deletes ds_write/ds_read/__syncthreads/waitcnt entirely.
//   - out[gid] stores are perfectly coalesced (contiguous across the wave).
//   - ids[r] is uniform per 32-lane half-wave -> single broadcast load.
__global__ __launch_bounds__(256) void gather_direct_kernel(
    const int* __restrict__ adj_ins, const int* __restrict__ adj_outs,
    const int* __restrict__ g_id_p, const int* __restrict__ ids,
    const int* __restrict__ ins_p, const SelArgs sel,
    int batch, int ns, int num_nodes, int degrees,
    int* __restrict__ out) {
  const long long gid = (long long)blockIdx.x * 256 + threadIdx.x;

  int r, j;
  if (ns == 32) {            // fast path: uniform branch, shift/mask
    r = (int)(gid >> 5);
    j = (int)(gid & 31);
  } else {
    r = (int)(gid / ns);
    j = (int)(gid - (long long)r * (long long)ns);
  }
  if (r >= batch) return;

  const int* adj = (*ins_p) ? adj_ins : adj_outs;
  const long long base =
      (long long)(*g_id_p) * (long long)num_nodes * (long long)degrees;

  const int node = ids[r];                       // broadcast within half-wave
  out[gid] = adj[base + (long long)node * (long long)degrees + sel.v[j]];
}

extern "C" void kernel_launch(void* const* d_in, const int* in_sizes, int n_in,
                              void* d_out, int out_size, void* d_ws, size_t ws_size,
                              hipStream_t stream) {
  const int* adj_ins  = (const int*)d_in[0];
  const int* adj_outs = (const int*)d_in[1];
  const int* g_id_p   = (const int*)d_in[2];
  const int* ids      = (const int*)d_in[3];
  const int* ins_p    = (const int*)d_in[5];

  const int batch = in_sizes[3];                 // 50000
  const int ns    = out_size / batch;            // 32
  const int NUM_NODES = 100000;
  const int DEGREES   = 128;

  // ---- host-side: sel = permutation(key(42), DEGREES)[:ns] ----
  // key(42) -> (0,42); partitionable split: subkey = block(key,(0,1));
  // bits[i] = hi^lo of block(subkey,(0,i)); stable argsort ascending.
  unsigned sk0, sk1;
  tf2x32_host(0u, 42u, 0u, 1u, sk0, sk1);
  unsigned bits[DEGREES];
  int perm[DEGREES];
  for (int i = 0; i < DEGREES; ++i) {
    unsigned b1, b2;
    tf2x32_host(sk0, sk1, 0u, (unsigned)i, b1, b2);
    bits[i] = b1 ^ b2;
    perm[i] = i;
  }
  std::stable_sort(perm, perm + DEGREES,
                   [&](int a, int b) { return bits[a] < bits[b]; });
  SelArgs sel{};
  const int ns_c = ns > MAX_NS ? MAX_NS : ns;
  for (int j = 0; j < ns_c; ++j) sel.v[j] = perm[j];

  const long long total = (long long)batch * (long long)ns;   // 1.6M
  const int nblocks = (int)((total + 255) / 256);             // 6250
  gather_direct_kernel<<<nblocks, 256, 0, stream>>>(
      adj_ins, adj_outs, g_id_p, ids, ins_p, sel,
      batch, ns, NUM_NODES, DEGREES, (int*)d_out);
}